// Round 6
// baseline (278.521 us; speedup 1.0000x reference)
//
#include <hip/hip_runtime.h>
#include <math.h>

#define V_ 32000
#define E_ 1024
#define H_ 1024
#define S_ 2048

typedef __attribute__((ext_vector_type(8))) short bf16x8;
typedef __attribute__((ext_vector_type(8))) unsigned short u16x8;
typedef __attribute__((ext_vector_type(4))) float f32x4;

typedef __attribute__((address_space(1))) const unsigned int gu32;
typedef __attribute__((address_space(3))) unsigned int lu32;

__device__ __forceinline__ float sigmoidf_(float x) { return 1.0f / (1.0f + expf(-x)); }

__device__ __forceinline__ unsigned short f2bf(float f) {
    unsigned int u = __builtin_bit_cast(unsigned int, f);
    unsigned int r = (u + 0x7fffu + ((u >> 16) & 1u)) >> 16;
    return (unsigned short)r;
}
__device__ __forceinline__ float bf2f(unsigned short u) {
    return __builtin_bit_cast(float, ((unsigned int)u) << 16);
}
__device__ __forceinline__ u16x8 pack8(float4 a, float4 b) {
    u16x8 p;
    p[0] = f2bf(a.x); p[1] = f2bf(a.y); p[2] = f2bf(a.z); p[3] = f2bf(a.w);
    p[4] = f2bf(b.x); p[5] = f2bf(b.y); p[6] = f2bf(b.z); p[7] = f2bf(b.w);
    return p;
}
__device__ __forceinline__ void gload16(const void* g, void* l) {
    __builtin_amdgcn_global_load_lds((gu32*)g, (lu32*)l, 16, 0, 0);
}

// release: all of this block's prior stores/atomics -> visible, then ctr++
__device__ __forceinline__ void phase_release(unsigned int* ctr) {
    __syncthreads();
    if (threadIdx.x == 0)
        __hip_atomic_fetch_add(ctr, 1u, __ATOMIC_RELEASE, __HIP_MEMORY_SCOPE_AGENT);
}
// acquire: wait until ctr == n, then invalidate caches for this CU
__device__ __forceinline__ void phase_acquire(unsigned int* ctr, unsigned int n) {
    if (threadIdx.x == 0) {
        while (__hip_atomic_load(ctr, __ATOMIC_ACQUIRE, __HIP_MEMORY_SCOPE_AGENT) < n)
            __builtin_amdgcn_s_sleep(8);
    }
    __syncthreads();
    __builtin_amdgcn_fence(__ATOMIC_ACQUIRE, "agent");
}

// ---------------- KA: LSTM (blocks 0..1023) || bf16 conversion (1024..1535) ----------------
__global__ __launch_bounds__(256) void kA(
    const float* __restrict__ W_ih, const float* __restrict__ W_hh,
    const float* __restrict__ b_ih, const float* __restrict__ b_hh,
    const float* __restrict__ last_context, const float* __restrict__ emb,
    const int* __restrict__ word, const float* __restrict__ h0,
    const float* __restrict__ c0, const float* __restrict__ enc,
    const float* __restrict__ W_attn,
    float* __restrict__ out_ht, float* __restrict__ out_c,
    float* __restrict__ ws_ht, unsigned short* __restrict__ encb,
    unsigned short* __restrict__ wab, float* __restrict__ ws_ctx,
    unsigned int* __restrict__ syncs)
{
    int b = blockIdx.x, tid = threadIdx.x;
    int wave = tid >> 6, lane = tid & 63;
    if (b < 1024) {
        __shared__ float sbuf[4];
        int j = b;
        const float* embrow = emb + (size_t)word[0] * E_;
        int row = j + wave * H_;
        const float* wi = W_ih + (size_t)row * (E_ + H_);
        const float* wh = W_hh + (size_t)row * H_;
        float acc = 0.f;
        #pragma unroll
        for (int it = 0; it < 8; ++it) {
            int idx = (lane + it * 64) * 4;
            float4 wv = *(const float4*)(wi + idx);
            float4 xv = (idx < H_) ? *(const float4*)(last_context + idx)
                                   : *(const float4*)(embrow + (idx - H_));
            acc = fmaf(wv.x, xv.x, acc); acc = fmaf(wv.y, xv.y, acc);
            acc = fmaf(wv.z, xv.z, acc); acc = fmaf(wv.w, xv.w, acc);
        }
        #pragma unroll
        for (int it = 0; it < 4; ++it) {
            int idx = (lane + it * 64) * 4;
            float4 wv = *(const float4*)(wh + idx);
            float4 hv = *(const float4*)(h0 + idx);
            acc = fmaf(wv.x, hv.x, acc); acc = fmaf(wv.y, hv.y, acc);
            acc = fmaf(wv.z, hv.z, acc); acc = fmaf(wv.w, hv.w, acc);
        }
        #pragma unroll
        for (int m = 32; m; m >>= 1) acc += __shfl_down(acc, m, 64);
        if (lane == 0) sbuf[wave] = acc;
        __syncthreads();
        if (tid == 0) {
            float gi = sbuf[0] + b_ih[j]          + b_hh[j];
            float gf = sbuf[1] + b_ih[j + H_]     + b_hh[j + H_];
            float gg = sbuf[2] + b_ih[j + 2*H_]   + b_hh[j + 2*H_];
            float go = sbuf[3] + b_ih[j + 3*H_]   + b_hh[j + 3*H_];
            float c  = sigmoidf_(gf) * c0[j] + sigmoidf_(gi) * tanhf(gg);
            float ht = sigmoidf_(go) * tanhf(c);
            out_c[j]  = c;
            out_ht[j] = ht;
            ws_ht[j]  = ht;
        }
        if (b == 0) {
            ws_ctx[tid]       = 0.f;
            ws_ctx[tid + 256] = 0.f;
            ws_ctx[tid + 512] = 0.f;
            ws_ctx[tid + 768] = 0.f;
            if (tid < 8) syncs[tid] = 0u;
        }
    } else {
        int cid = (b - 1024) * 256 + tid;
        const int ENC_CH = (S_ * E_) / 8;   // 262144
        #pragma unroll
        for (int i = 0; i < 3; ++i) {
            int idx = cid + i * 131072;
            const float* src;
            unsigned short* dst;
            if (idx < ENC_CH) {
                src = enc + (size_t)idx * 8;
                dst = encb + (size_t)idx * 8;
            } else {
                int w = idx - ENC_CH;
                int h = w >> 7, off = (w & 127) * 8;
                src = W_attn + (size_t)h * (E_ + H_) + H_ + off;
                dst = wab + (size_t)h * E_ + off;
            }
            float4 a = *(const float4*)src;
            float4 bq = *(const float4*)(src + 4);
            *(u16x8*)dst = pack8(a, bq);
        }
    }
}

// ---------------- KBC: q = Wa_h@ht + b_attn (phase 0), then scores GEMM ----------------
// grid (16,16) = 256 blocks, 256 thr. Spin for q sits AFTER the GEMM main loop.
__global__ __launch_bounds__(256) void kBC(
    const float* __restrict__ W_attn, const float* __restrict__ b_attn,
    const float* __restrict__ ws_ht,
    const unsigned short* __restrict__ encb, const unsigned short* __restrict__ wab,
    const float* __restrict__ v,
    float* __restrict__ ws_q, float* __restrict__ spart,
    unsigned int* __restrict__ syncs)
{
    __shared__ unsigned short As[2][128 * 64];
    __shared__ unsigned short Bs[2][64 * 64];
    int bx = blockIdx.x, by = blockIdx.y;
    int b = by * 16 + bx;
    int tid = threadIdx.x;
    int wave = tid >> 6, lane = tid & 63;

    // ---- phase 0: q rows b*4 .. b*4+3, one per wave ----
    {
        int r = b * 4 + wave;
        const float* rowp = W_attn + (size_t)r * (E_ + H_);
        float acc = 0.f;
        #pragma unroll
        for (int it = 0; it < 4; ++it) {
            int idx = (lane + it * 64) * 4;
            float4 wv = *(const float4*)(rowp + idx);
            float4 hv = *(const float4*)(ws_ht + idx);
            acc = fmaf(wv.x, hv.x, acc); acc = fmaf(wv.y, hv.y, acc);
            acc = fmaf(wv.z, hv.z, acc); acc = fmaf(wv.w, hv.w, acc);
        }
        #pragma unroll
        for (int m = 32; m; m >>= 1) acc += __shfl_down(acc, m, 64);
        if (lane == 0) ws_q[r] = acc + b_attn[r];
    }
    phase_release(&syncs[0]);

    // ---- GEMM main loop (doesn't need q) ----
    int s0 = bx * 128, h0 = by * 64;
    int srow = tid >> 3;
    int lch  = ((tid & 7) ^ (srow & 7)) * 8;
    const unsigned short* aSrc[4];
    #pragma unroll
    for (int jj = 0; jj < 4; ++jj)
        aSrc[jj] = encb + (size_t)(s0 + jj * 32 + srow) * E_ + lch;
    const unsigned short* bSrc[2];
    #pragma unroll
    for (int jj = 0; jj < 2; ++jj)
        bSrc[jj] = wab + (size_t)(h0 + jj * 32 + srow) * E_ + lch;

    int wr = (wave >> 1) * 64, wc = (wave & 1) * 32;
    int fc = lane & 15, g = lane >> 4;
    int aRow[4], bRow[2], pc[2];
    #pragma unroll
    for (int m = 0; m < 4; ++m) aRow[m] = (wr + m * 16 + fc) * 64;
    #pragma unroll
    for (int n = 0; n < 2; ++n) bRow[n] = (wc + n * 16 + fc) * 64;
    #pragma unroll
    for (int kk = 0; kk < 2; ++kk) pc[kk] = ((kk * 4 + g) ^ (fc & 7)) * 8;

    f32x4 acc[4][2];
    #pragma unroll
    for (int m = 0; m < 4; ++m)
        #pragma unroll
        for (int n = 0; n < 2; ++n)
            acc[m][n] = (f32x4){0.f, 0.f, 0.f, 0.f};

    #pragma unroll
    for (int jj = 0; jj < 4; ++jj) gload16(aSrc[jj], &As[0][jj * 2048 + tid * 8]);
    #pragma unroll
    for (int jj = 0; jj < 2; ++jj) gload16(bSrc[jj], &Bs[0][jj * 2048 + tid * 8]);
    __syncthreads();

    int cur = 0;
    for (int t = 0; t < 16; ++t) {
        if (t < 15) {
            int k0 = (t + 1) * 64;
            #pragma unroll
            for (int jj = 0; jj < 4; ++jj)
                gload16(aSrc[jj] + k0, &As[cur ^ 1][jj * 2048 + tid * 8]);
            #pragma unroll
            for (int jj = 0; jj < 2; ++jj)
                gload16(bSrc[jj] + k0, &Bs[cur ^ 1][jj * 2048 + tid * 8]);
        }
        #pragma unroll
        for (int kk = 0; kk < 2; ++kk) {
            bf16x8 af[4], bf2[2];
            #pragma unroll
            for (int m = 0; m < 4; ++m) af[m] = *(const bf16x8*)&As[cur][aRow[m] + pc[kk]];
            #pragma unroll
            for (int n = 0; n < 2; ++n) bf2[n] = *(const bf16x8*)&Bs[cur][bRow[n] + pc[kk]];
            #pragma unroll
            for (int m = 0; m < 4; ++m)
                #pragma unroll
                for (int n = 0; n < 2; ++n)
                    acc[m][n] = __builtin_amdgcn_mfma_f32_16x16x32_bf16(
                        af[m], bf2[n], acc[m][n], 0, 0, 0);
        }
        __syncthreads();
        cur ^= 1;
    }

    // ---- wait for all q rows, then epilogue ----
    phase_acquire(&syncs[0], 256u);

    float qv[2], vv[2];
    #pragma unroll
    for (int n = 0; n < 2; ++n) {
        int col = h0 + wc + n * 16 + fc;
        qv[n] = ws_q[col];
        vv[n] = v[col];
    }
    int part = by * 2 + (wave & 1);
    #pragma unroll
    for (int m = 0; m < 4; ++m) {
        #pragma unroll
        for (int j = 0; j < 4; ++j) {
            float p = 0.f;
            #pragma unroll
            for (int n = 0; n < 2; ++n)
                p += tanhf(acc[m][n][j] + qv[n]) * vv[n];
            #pragma unroll
            for (int mask = 8; mask; mask >>= 1) p += __shfl_xor(p, mask, 64);
            if (fc == 0)
                spart[(size_t)(s0 + wr + m * 16 + g * 4 + j) * 32 + part] = p;
        }
    }
}

// ---------------- KDE: exp/gpart/ctxU (D) -> spin -> invS, ht_tilda, out_w (E) ----------------
// 256 blocks x 256 thr; block owns 8 s-rows (D) and 4 h-rows (E).
__global__ __launch_bounds__(256) void kDE(
    const float* __restrict__ spart, const unsigned short* __restrict__ encb,
    const float* __restrict__ W_ah, const float* __restrict__ b_ah,
    const float* __restrict__ ws_ht,
    float* __restrict__ gpart, float* __restrict__ ctx,
    float* __restrict__ out_htt, float* __restrict__ ws_htt,
    float* __restrict__ out_w, unsigned int* __restrict__ syncs)
{
    __shared__ float esh[8];
    __shared__ float sred[4];
    int b = blockIdx.x, tid = threadIdx.x;
    int wave = tid >> 6, lane = tid & 63;
    int s0 = b * 8;
    // ---- D: scores -> exp ----
    int sl = tid >> 5, pp = tid & 31;
    float vsum = spart[(size_t)(s0 + sl) * 32 + pp];
    #pragma unroll
    for (int m = 16; m; m >>= 1) vsum += __shfl_xor(vsum, m, 64);
    if (pp == 0) esh[sl] = expf(vsum);
    __syncthreads();
    if (tid == 0) {
        float bs = 0.f;
        #pragma unroll
        for (int i = 0; i < 8; ++i) bs += esh[i];
        gpart[b] = bs;
    }
    // ---- D: unnormalized context ----
    int e0 = tid * 4;
    float a0 = 0.f, a1 = 0.f, a2 = 0.f, a3 = 0.f;
    #pragma unroll
    for (int ss = 0; ss < 8; ++ss) {
        ushort4 u = *(const ushort4*)(encb + (size_t)(s0 + ss) * E_ + e0);
        float w = esh[ss];
        a0 = fmaf(w, bf2f(u.x), a0);
        a1 = fmaf(w, bf2f(u.y), a1);
        a2 = fmaf(w, bf2f(u.z), a2);
        a3 = fmaf(w, bf2f(u.w), a3);
    }
    atomicAdd(&ctx[e0 + 0], a0);
    atomicAdd(&ctx[e0 + 1], a1);
    atomicAdd(&ctx[e0 + 2], a2);
    atomicAdd(&ctx[e0 + 3], a3);
    phase_release(&syncs[1]);
    phase_acquire(&syncs[1], 256u);
    // ---- E: invS ----
    float gv = gpart[tid];
    #pragma unroll
    for (int m = 32; m; m >>= 1) gv += __shfl_xor(gv, m, 64);
    if (lane == 0) sred[wave] = gv;
    __syncthreads();
    float invS = 1.0f / (sred[0] + sred[1] + sred[2] + sred[3]);
    // ---- E: ht_tilda row r = b*4 + wave ----
    {
        int r = b * 4 + wave;
        const float* rowp = W_ah + (size_t)r * (E_ + H_);
        float acc = 0.f;
        #pragma unroll
        for (int it = 0; it < 8; ++it) {
            int idx = (lane + it * 64) * 4;
            float4 wv = *(const float4*)(rowp + idx);
            float4 xv;
            if (idx < E_) {
                float4 cv = *(const float4*)(ctx + idx);
                xv = (float4){ cv.x * invS, cv.y * invS, cv.z * invS, cv.w * invS };
            } else {
                xv = *(const float4*)(ws_ht + idx - E_);
            }
            acc = fmaf(wv.x, xv.x, acc); acc = fmaf(wv.y, xv.y, acc);
            acc = fmaf(wv.z, xv.z, acc); acc = fmaf(wv.w, xv.w, acc);
        }
        #pragma unroll
        for (int m = 32; m; m >>= 1) acc += __shfl_down(acc, m, 64);
        if (lane == 0) {
            float val = tanhf(acc + b_ah[r]);
            out_htt[r] = val;
            ws_htt[r]  = val;
        }
    }
    // ---- E: out_w for own 8 s-rows ----
    if (tid < 8) out_w[s0 + tid] = esh[tid] * invS;
}

// ---------------- KFG: logits + expsum -> spin -> lse -> subtract ----------------
// 1000 blocks x 256 thr (32 rows/block); min 4 blocks/CU guaranteed.
__global__ __launch_bounds__(256, 4) void kFG(
    const float* __restrict__ W_out, const float* __restrict__ b_out,
    const float* __restrict__ htt, float* __restrict__ logits,
    unsigned int* __restrict__ syncs)
{
    __shared__ float wes[4];
    __shared__ float slse;
    int b = blockIdx.x, tid = threadIdx.x;
    int wave = tid >> 6, lane = tid & 63;
    float esum = 0.f;
    #pragma unroll
    for (int k = 0; k < 8; ++k) {
        int row = b * 32 + wave * 8 + k;
        const float* wr = W_out + (size_t)row * H_;
        float acc = 0.f;
        #pragma unroll
        for (int it = 0; it < 4; ++it) {
            int idx = (lane + it * 64) * 4;
            float4 wv = *(const float4*)(wr + idx);
            float4 hv = *(const float4*)(htt + idx);
            acc = fmaf(wv.x, hv.x, acc); acc = fmaf(wv.y, hv.y, acc);
            acc = fmaf(wv.z, hv.z, acc); acc = fmaf(wv.w, hv.w, acc);
        }
        #pragma unroll
        for (int m = 32; m; m >>= 1) acc += __shfl_down(acc, m, 64);
        if (lane == 0) {
            float lg = acc + b_out[row];
            logits[row] = lg;
            esum += expf(lg);
        }
    }
    if (lane == 0) wes[wave] = esum;
    __syncthreads();
    if (tid == 0) {
        float bs = wes[0] + wes[1] + wes[2] + wes[3];
        atomicAdd((float*)&syncs[4], bs);
        __hip_atomic_fetch_add(&syncs[2], 1u, __ATOMIC_RELEASE, __HIP_MEMORY_SCOPE_AGENT);
        while (__hip_atomic_load(&syncs[2], __ATOMIC_ACQUIRE, __HIP_MEMORY_SCOPE_AGENT) < 1000u)
            __builtin_amdgcn_s_sleep(8);
        float gsl = __hip_atomic_load((float*)&syncs[4], __ATOMIC_RELAXED, __HIP_MEMORY_SCOPE_AGENT);
        slse = logf(gsl);
    }
    __syncthreads();
    if (tid < 32) logits[b * 32 + tid] -= slse;
}

extern "C" void kernel_launch(void* const* d_in, const int* in_sizes, int n_in,
                              void* d_out, int out_size, void* d_ws, size_t ws_size,
                              hipStream_t stream) {
    const float* enc          = (const float*)d_in[0];
    const int*   word         = (const int*)  d_in[1];
    const float* last_context = (const float*)d_in[2];
    const float* h0           = (const float*)d_in[3];
    const float* c0           = (const float*)d_in[4];
    const float* emb          = (const float*)d_in[5];
    const float* W_ih         = (const float*)d_in[6];
    const float* W_hh         = (const float*)d_in[7];
    const float* b_ih         = (const float*)d_in[8];
    const float* b_hh         = (const float*)d_in[9];
    const float* W_attn       = (const float*)d_in[10];
    const float* b_attn       = (const float*)d_in[11];
    const float* v            = (const float*)d_in[12];
    const float* W_ah         = (const float*)d_in[13];
    const float* b_ah         = (const float*)d_in[14];
    const float* W_out        = (const float*)d_in[15];
    const float* b_out        = (const float*)d_in[16];

    float* out        = (float*)d_out;
    float* out_logits = out;                 // 32000
    float* out_ht     = out + V_;            // 1024
    float* out_c      = out + V_ + H_;       // 1024
    float* out_htt    = out + V_ + 2 * H_;   // 1024
    float* out_w      = out + V_ + 3 * H_;   // 2048

    float* ws       = (float*)d_ws;
    float* ws_ht    = ws;              // 1024
    float* ws_q     = ws + 1024;       // 1024
    float* ws_htt   = ws + 2048;       // 1024
    float* ws_gp    = ws + 3072;       // 256
    float* ws_ctx   = ws + 3328;       // 1024
    unsigned int* syncs = (unsigned int*)(ws + 4352);  // 8
    float* ws_sp    = ws + 8192;       // 2048*32
    unsigned short* encb = (unsigned short*)(ws + 81920);  // 2048*1024 bf16
    unsigned short* wab  = encb + (size_t)S_ * E_;         // 1024*1024 bf16

    kA<<<1536, 256, 0, stream>>>(W_ih, W_hh, b_ih, b_hh, last_context, emb, word,
                                 h0, c0, enc, W_attn, out_ht, out_c, ws_ht,
                                 encb, wab, ws_ctx, syncs);
    kBC<<<dim3(16, 16), 256, 0, stream>>>(W_attn, b_attn, ws_ht, encb, wab, v,
                                          ws_q, ws_sp, syncs);
    kDE<<<256, 256, 0, stream>>>(ws_sp, encb, W_ah, b_ah, ws_ht,
                                 ws_gp, ws_ctx, out_htt, ws_htt, out_w, syncs);
    kFG<<<1000, 256, 0, stream>>>(W_out, b_out, ws_htt, out_logits, syncs);
}